// Round 1
// baseline (3007.997 us; speedup 1.0000x reference)
//
#include <hip/hip_runtime.h>
#include <math.h>

#define S_LEN 2048
#define HD    2048
#define DHEAD 128
#define NH    16
#define NKVH  4
#define FDIM  4096
#define NE    8
#define KVW   (NKVH*DHEAD)   // 512

typedef unsigned short u16;
typedef __bf16 bf16x8 __attribute__((ext_vector_type(8)));
typedef float f32x4 __attribute__((ext_vector_type(4)));
typedef u16 u16x8 __attribute__((ext_vector_type(8)));
typedef u16 u16x4 __attribute__((ext_vector_type(4)));

__device__ inline u16 f2bf(float f) {
  unsigned u = __float_as_uint(f);
  unsigned r = (u + 0x7fffu + ((u >> 16) & 1u)) >> 16;
  return (u16)r;
}
__device__ inline float bf2f(u16 h) { return __uint_as_float((unsigned)h << 16); }

__device__ inline f32x4 mfma16(bf16x8 a, bf16x8 b, f32x4 c) {
  return __builtin_amdgcn_mfma_f32_16x16x32_bf16(a, b, c, 0, 0, 0);
}

// global -> LDS direct copy, 16B per lane; lds ptr must be uniform-base + lane*16
#define GLL16(g, l) __builtin_amdgcn_global_load_lds( \
    (__attribute__((address_space(1))) void*)(void*)(g), \
    (__attribute__((address_space(3))) void*)(l), 16, 0, 0)

// ---------------- fp32 -> bf16 hi/lo split ----------------------------------
__global__ __launch_bounds__(256) void cvt_split_kernel(const float* __restrict__ in,
    u16* __restrict__ hi, u16* __restrict__ lo, size_t n4) {
  for (size_t i = (size_t)blockIdx.x * 256 + threadIdx.x; i < n4; i += (size_t)gridDim.x * 256) {
    float4 v = ((const float4*)in)[i];
    u16x4 h, l;
    float f[4] = {v.x, v.y, v.z, v.w};
    #pragma unroll
    for (int j = 0; j < 4; j++) {
      u16 hh = f2bf(f[j]);
      h[j] = hh;
      l[j] = f2bf(f[j] - bf2f(hh));
    }
    ((u16x4*)hi)[i] = h;
    ((u16x4*)lo)[i] = l;
  }
}

// ---------------- RMSNorm writing optional fp32 + bf16 hi/lo ----------------
__global__ __launch_bounds__(256) void rmsnorm_split_kernel(const float* __restrict__ x,
    const float* __restrict__ w, float* __restrict__ outf,
    u16* __restrict__ oh, u16* __restrict__ ol) {
  int row = blockIdx.x;
  const float* xr = x + (size_t)row * HD;
  float ss = 0.f;
  for (int i = threadIdx.x; i < HD; i += 256) { float v = xr[i]; ss += v * v; }
  #pragma unroll
  for (int off = 32; off > 0; off >>= 1) ss += __shfl_xor(ss, off, 64);
  __shared__ float red[4];
  int lane = threadIdx.x & 63, wid = threadIdx.x >> 6;
  if (lane == 0) red[wid] = ss;
  __syncthreads();
  float tot = red[0] + red[1] + red[2] + red[3];
  float scale = rsqrtf(tot * (1.0f / HD) + 1e-5f);
  for (int i = threadIdx.x; i < HD; i += 256) {
    float v = xr[i] * scale * w[i];
    if (outf) outf[(size_t)row * HD + i] = v;
    u16 hh = f2bf(v);
    oh[(size_t)row * HD + i] = hh;
    ol[(size_t)row * HD + i] = f2bf(v - bf2f(hh));
  }
}

// ---------------- split-bf16 MFMA GEMM: C[M,N] = A[M,K] @ B[N,K]^T ----------
// A,B given as hi/lo bf16 pairs. 128x128 tile, BK=32, 4 waves.
__global__ __launch_bounds__(256) void gemm_mfma(
    const u16* __restrict__ Ah, const u16* __restrict__ Al,
    const u16* __restrict__ Bh, const u16* __restrict__ Bl,
    const float* __restrict__ residual, float* __restrict__ C, float* __restrict__ C2,
    int M, int N, int K) {
  __shared__ u16 sAh[128 * 32], sAl[128 * 32], sBh[128 * 32], sBl[128 * 32];
  int tid = threadIdx.x;
  int wid = tid >> 6, lane = tid & 63;
  int m0 = blockIdx.y * 128, n0 = blockIdx.x * 128;
  int wr = (wid >> 1) * 64, wc = (wid & 1) * 64;
  int ar0 = tid >> 2, ac = (tid & 3) * 8;   // chunk row 0..63, col offset
  int ar1 = ar0 + 64;
  f32x4 acc[4][4] = {};
  int fr = lane & 15, fk = (lane >> 4) * 8;
  for (int k0 = 0; k0 < K; k0 += 32) {
    size_t ga0 = (size_t)(m0 + ar0) * K + k0 + ac;
    size_t ga1 = (size_t)(m0 + ar1) * K + k0 + ac;
    size_t gb0 = (size_t)(n0 + ar0) * K + k0 + ac;
    size_t gb1 = (size_t)(n0 + ar1) * K + k0 + ac;
    GLL16(Ah + ga0, sAh + tid * 8);
    GLL16(Ah + ga1, sAh + (tid + 256) * 8);
    GLL16(Al + ga0, sAl + tid * 8);
    GLL16(Al + ga1, sAl + (tid + 256) * 8);
    GLL16(Bh + gb0, sBh + tid * 8);
    GLL16(Bh + gb1, sBh + (tid + 256) * 8);
    GLL16(Bl + gb0, sBl + tid * 8);
    GLL16(Bl + gb1, sBl + (tid + 256) * 8);
    __syncthreads();
    bf16x8 ah[4], al[4], bh[4], bl[4];
    #pragma unroll
    for (int i = 0; i < 4; i++) {
      int rowA = wr + i * 16 + fr;
      int rowB = wc + i * 16 + fr;
      ah[i] = *(const bf16x8*)(sAh + rowA * 32 + fk);
      al[i] = *(const bf16x8*)(sAl + rowA * 32 + fk);
      bh[i] = *(const bf16x8*)(sBh + rowB * 32 + fk);
      bl[i] = *(const bf16x8*)(sBl + rowB * 32 + fk);
    }
    #pragma unroll
    for (int i = 0; i < 4; i++)
      #pragma unroll
      for (int j = 0; j < 4; j++) {
        acc[i][j] = mfma16(ah[i], bh[j], acc[i][j]);
        acc[i][j] = mfma16(ah[i], bl[j], acc[i][j]);
        acc[i][j] = mfma16(al[i], bh[j], acc[i][j]);
      }
    __syncthreads();
  }
  int cc = lane & 15, cr = (lane >> 4) * 4;
  #pragma unroll
  for (int i = 0; i < 4; i++) {
    #pragma unroll
    for (int r = 0; r < 4; r++) {
      int gm = m0 + wr + i * 16 + cr + r;
      #pragma unroll
      for (int j = 0; j < 4; j++) {
        int gn = n0 + wc + j * 16 + cc;
        float v = acc[i][j][r];
        if (residual) v += residual[(size_t)gm * N + gn];
        C[(size_t)gm * N + gn] = v;
        if (C2) C2[(size_t)gm * N + gn] = v;
      }
    }
  }
}

// ---------------- RoPE in-place on q [S,16*128] and k [S,4*128] --------------
__global__ __launch_bounds__(256) void rope_kernel(float* __restrict__ q, float* __restrict__ k) {
  int s = blockIdx.x;
  const float LOG_THETA = 9.210340371976184f; // ln(10000)
  for (int i = threadIdx.x; i < (NH + NKVH) * 64; i += 256) {
    int h = i >> 6, d = i & 63;
    float invf = expf(-(float)d * (1.0f / 64.0f) * LOG_THETA);
    float ang = (float)s * invf;
    float sn, cs;
    sincosf(ang, &sn, &cs);
    float* base = (h < NH) ? (q + (size_t)s * HD + h * DHEAD)
                           : (k + (size_t)s * KVW + (h - NH) * DHEAD);
    float x0 = base[d], x1 = base[d + 64];
    base[d]      = x0 * cs - x1 * sn;
    base[d + 64] = x1 * cs + x0 * sn;
  }
}

// ---------------- Flash-style causal attention -------------------------------
#define QT 32
#define KT 32
__global__ __launch_bounds__(256) void attn_kernel(const float* __restrict__ q,
    const float* __restrict__ k, const float* __restrict__ v, float* __restrict__ out) {
  __shared__ __align__(16) float Qs[QT][132];
  __shared__ __align__(16) float Ks[KT][132];
  __shared__ __align__(16) float Vs[KT][132];
  int h = blockIdx.y, qt = blockIdx.x;
  int g = h >> 2;  // kv head (groups = 4)
  int tid = threadIdx.x;
  int ql = tid >> 3, ks = tid & 7;
  int lane = tid & 63;
  for (int idx = tid; idx < QT * DHEAD; idx += 256) {
    int r = idx >> 7, d = idx & 127;
    Qs[r][d] = q[(size_t)(qt * QT + r) * HD + h * DHEAD + d];
  }
  float4 acc[4] = {};
  float m_run = -1e30f, l_run = 0.f;
  int qg = qt * QT + ql;
  for (int kt = 0; kt <= qt; kt++) {
    __syncthreads();
    for (int idx = tid; idx < KT * DHEAD; idx += 256) {
      int r = idx >> 7, d = idx & 127;
      size_t src = (size_t)(kt * KT + r) * KVW + g * DHEAD + d;
      Ks[r][d] = k[src];
      Vs[r][d] = v[src];
    }
    __syncthreads();
    float s[4] = {0.f, 0.f, 0.f, 0.f};
    const float4* Q4 = (const float4*)&Qs[ql][0];
    #pragma unroll 8
    for (int d4 = 0; d4 < 32; d4++) {
      float4 qv = Q4[d4];
      #pragma unroll
      for (int jj = 0; jj < 4; jj++) {
        float4 kv = ((const float4*)&Ks[ks * 4 + jj][0])[d4];
        s[jj] += qv.x * kv.x + qv.y * kv.y + qv.z * kv.z + qv.w * kv.w;
      }
    }
    float mloc = -1e30f;
    #pragma unroll
    for (int jj = 0; jj < 4; jj++) {
      int kjg = kt * KT + ks * 4 + jj;
      s[jj] = (kjg <= qg) ? s[jj] * 0.088388347648318447f : -1e30f;
      mloc = fmaxf(mloc, s[jj]);
    }
    #pragma unroll
    for (int off = 1; off < 8; off <<= 1) mloc = fmaxf(mloc, __shfl_xor(mloc, off, 64));
    float m_new = fmaxf(m_run, mloc);
    float alpha = expf(m_run - m_new);
    float p[4], lloc = 0.f;
    #pragma unroll
    for (int jj = 0; jj < 4; jj++) { p[jj] = expf(s[jj] - m_new); lloc += p[jj]; }
    #pragma unroll
    for (int off = 1; off < 8; off <<= 1) lloc += __shfl_xor(lloc, off, 64);
    l_run = l_run * alpha + lloc;
    m_run = m_new;
    #pragma unroll
    for (int qi = 0; qi < 4; qi++) {
      acc[qi].x *= alpha; acc[qi].y *= alpha; acc[qi].z *= alpha; acc[qi].w *= alpha;
    }
    #pragma unroll
    for (int j = 0; j < 32; j++) {
      float pj = __shfl(p[j & 3], (lane & 56) | (j >> 2), 64);
      #pragma unroll
      for (int qi = 0; qi < 4; qi++) {
        float4 vv = ((const float4*)&Vs[j][0])[ks * 4 + qi];
        acc[qi].x += pj * vv.x; acc[qi].y += pj * vv.y;
        acc[qi].z += pj * vv.z; acc[qi].w += pj * vv.w;
      }
    }
  }
  float inv_l = 1.0f / l_run;
  float4* o4 = (float4*)(out + (size_t)qg * HD + h * DHEAD + ks * 16);
  #pragma unroll
  for (int qi = 0; qi < 4; qi++) {
    float4 r;
    r.x = acc[qi].x * inv_l; r.y = acc[qi].y * inv_l;
    r.z = acc[qi].z * inv_l; r.w = acc[qi].w * inv_l;
    o4[qi] = r;
  }
}

// ---------------- MoE routing: logits -> softmax -> top2 ---------------------
__global__ __launch_bounds__(256) void route_kernel(const float* __restrict__ x2,
    const float* __restrict__ gw, int* __restrict__ tok_e, float* __restrict__ tok_w,
    int* __restrict__ counts) {
  int t = blockIdx.x;
  const float* xr = x2 + (size_t)t * HD;
  float acc[NE] = {};
  for (int i = threadIdx.x; i < HD; i += 256) {
    float xv = xr[i];
    #pragma unroll
    for (int e = 0; e < NE; e++) acc[e] += xv * gw[e * HD + i];
  }
  #pragma unroll
  for (int e = 0; e < NE; e++) {
    float vv = acc[e];
    #pragma unroll
    for (int off = 32; off > 0; off >>= 1) vv += __shfl_xor(vv, off, 64);
    acc[e] = vv;
  }
  __shared__ float red[4][NE];
  int lane = threadIdx.x & 63, wid = threadIdx.x >> 6;
  if (lane == 0) {
    #pragma unroll
    for (int e = 0; e < NE; e++) red[wid][e] = acc[e];
  }
  __syncthreads();
  if (threadIdx.x == 0) {
    float l[NE];
    float mx = -1e30f;
    #pragma unroll
    for (int e = 0; e < NE; e++) { l[e] = red[0][e] + red[1][e] + red[2][e] + red[3][e]; mx = fmaxf(mx, l[e]); }
    float ex[NE];
    #pragma unroll
    for (int e = 0; e < NE; e++) ex[e] = expf(l[e] - mx);
    int i0 = 0;
    #pragma unroll
    for (int e = 1; e < NE; e++) if (ex[e] > ex[i0]) i0 = e;
    int i1 = (i0 == 0) ? 1 : 0;
    #pragma unroll
    for (int e = 0; e < NE; e++) if (e != i0 && ex[e] > ex[i1]) i1 = e;
    float denom = ex[i0] + ex[i1];
    tok_e[2 * t] = i0; tok_e[2 * t + 1] = i1;
    tok_w[2 * t] = ex[i0] / denom; tok_w[2 * t + 1] = ex[i1] / denom;
    atomicAdd(&counts[i0], 1);
    atomicAdd(&counts[i1], 1);
  }
}

__global__ void zero_counts_kernel(int* counts) {
  if (threadIdx.x < NE) counts[threadIdx.x] = 0;
}

__global__ void offsets_kernel(const int* __restrict__ counts, int* __restrict__ offs,
                               int* __restrict__ ctr2) {
  if (threadIdx.x == 0) {
    int s = 0;
    for (int e = 0; e < NE; e++) { offs[e] = s; s += counts[e]; ctr2[e] = 0; }
  }
}

__global__ __launch_bounds__(256) void scatter_kernel(const int* __restrict__ tok_e,
    const float* __restrict__ tok_w, const int* __restrict__ offs, int* __restrict__ ctr2,
    int* __restrict__ slot_tok, float* __restrict__ slot_w) {
  int i = blockIdx.x * 256 + threadIdx.x;
  if (i >= 2 * S_LEN) return;
  int e = tok_e[i];
  int pos = offs[e] + atomicAdd(&ctr2[e], 1);
  slot_tok[pos] = i >> 1;
  slot_w[pos] = tok_w[i];
}

// ---------------- MoE stage 1: act = silu(x2@w1^T) * (x2@w3^T), MFMA --------
// BM=128, BN=64. A = gathered x2 (hi/lo, pre-split, via global_load_lds).
// B1/B3 = w1/w3 rows, fp32 in global, split to bf16 hi/lo on the fly.
__global__ __launch_bounds__(256) void moe1_mfma(const u16* __restrict__ x2h,
    const u16* __restrict__ x2l, const float* __restrict__ w1,
    const float* __restrict__ w3, const int* __restrict__ counts,
    const int* __restrict__ offs, const int* __restrict__ slot_tok,
    u16* __restrict__ acth, u16* __restrict__ actl) {
  int e = blockIdx.z;
  int ne = counts[e];
  int m0 = blockIdx.y * 128;
  if (m0 >= ne) return;
  int n0 = blockIdx.x * 64;
  __shared__ u16 sAh[128 * 32], sAl[128 * 32];
  __shared__ u16 sB1h[64 * 32], sB1l[64 * 32], sB3h[64 * 32], sB3l[64 * 32];
  int tid = threadIdx.x;
  int base = offs[e];
  int ar0 = tid >> 2, ac = (tid & 3) * 8;
  int ar1 = ar0 + 64;
  int i0 = m0 + ar0; if (i0 > ne - 1) i0 = ne - 1;
  int i1 = m0 + ar1; if (i1 > ne - 1) i1 = ne - 1;
  int tok0 = slot_tok[base + i0];
  int tok1 = slot_tok[base + i1];
  const float* W1 = w1 + (size_t)e * FDIM * HD;
  const float* W3 = w3 + (size_t)e * FDIM * HD;
  int wid = tid >> 6, lane = tid & 63;
  int wr = (wid >> 1) * 64, wc = (wid & 1) * 32;
  int fr = lane & 15, fk = (lane >> 4) * 8;
  f32x4 acc1[4][2] = {}, acc3[4][2] = {};
  for (int k0 = 0; k0 < HD; k0 += 32) {
    GLL16(x2h + (size_t)tok0 * HD + k0 + ac, sAh + tid * 8);
    GLL16(x2h + (size_t)tok1 * HD + k0 + ac, sAh + (tid + 256) * 8);
    GLL16(x2l + (size_t)tok0 * HD + k0 + ac, sAl + tid * 8);
    GLL16(x2l + (size_t)tok1 * HD + k0 + ac, sAl + (tid + 256) * 8);
    {
      const float* g1 = W1 + (size_t)(n0 + ar0) * HD + k0 + ac;
      const float* g3 = W3 + (size_t)(n0 + ar0) * HD + k0 + ac;
      float f1[8], f3[8];
      *(float4*)&f1[0] = *(const float4*)g1;
      *(float4*)&f1[4] = *(const float4*)(g1 + 4);
      *(float4*)&f3[0] = *(const float4*)g3;
      *(float4*)&f3[4] = *(const float4*)(g3 + 4);
      u16x8 h1, l1, h3, l3;
      #pragma unroll
      for (int i = 0; i < 8; i++) {
        u16 hh = f2bf(f1[i]); h1[i] = hh; l1[i] = f2bf(f1[i] - bf2f(hh));
        u16 gg = f2bf(f3[i]); h3[i] = gg; l3[i] = f2bf(f3[i] - bf2f(gg));
      }
      *(u16x8*)(sB1h + tid * 8) = h1;
      *(u16x8*)(sB1l + tid * 8) = l1;
      *(u16x8*)(sB3h + tid * 8) = h3;
      *(u16x8*)(sB3l + tid * 8) = l3;
    }
    __syncthreads();
    bf16x8 ah[4], al[4];
    #pragma unroll
    for (int i = 0; i < 4; i++) {
      int row = wr + i * 16 + fr;
      ah[i] = *(const bf16x8*)(sAh + row * 32 + fk);
      al[i] = *(const bf16x8*)(sAl + row * 32 + fk);
    }
    bf16x8 b1h[2], b1l[2], b3h[2], b3l[2];
    #pragma unroll
    for (int j = 0; j < 2; j++) {
      int row = wc + j * 16 + fr;
      b1h[j] = *(const bf16x8*)(sB1h + row * 32 + fk);
      b1l[j] = *(const bf16x8*)(sB1l + row * 32 + fk);
      b3h[j] = *(const bf16x8*)(sB3h + row * 32 + fk);
      b3l[j] = *(const bf16x8*)(sB3l + row * 32 + fk);
    }
    #pragma unroll
    for (int i = 0; i < 4; i++)
      #pragma unroll
      for (int j = 0; j < 2; j++) {
        acc1[i][j] = mfma16(ah[i], b1h[j], acc1[i][j]);
        acc1[i][j] = mfma16(ah[i], b1l[j], acc1[i][j]);
        acc1[i][j] = mfma16(al[i], b1h[j], acc1[i][j]);
        acc3[i][j] = mfma16(ah[i], b3h[j], acc3[i][j]);
        acc3[i][j] = mfma16(ah[i], b3l[j], acc3[i][j]);
        acc3[i][j] = mfma16(al[i], b3h[j], acc3[i][j]);
      }
    __syncthreads();
  }
  int cc = lane & 15, cr = (lane >> 4) * 4;
  #pragma unroll
  for (int i = 0; i < 4; i++) {
    #pragma unroll
    for (int r = 0; r < 4; r++) {
      int gm = m0 + wr + i * 16 + cr + r;
      if (gm >= ne) continue;
      size_t orow = (size_t)(base + gm) * FDIM;
      #pragma unroll
      for (int j = 0; j < 2; j++) {
        int gn = n0 + wc + j * 16 + cc;
        float g = acc1[i][j][r], uu = acc3[i][j][r];
        float val = g / (1.f + expf(-g)) * uu;
        u16 hh = f2bf(val);
        acth[orow + gn] = hh;
        actl[orow + gn] = f2bf(val - bf2f(hh));
      }
    }
  }
}

// ---------------- MoE stage 2: out[tok] += wt * (act @ w2^T), MFMA ----------
// BM=128, BN=128. A = act segment (hi/lo bf16 via global_load_lds, clamped).
// B = w2 rows, fp32 split on the fly.
__global__ __launch_bounds__(256) void moe2_mfma(const u16* __restrict__ acth,
    const u16* __restrict__ actl, const float* __restrict__ w2,
    const int* __restrict__ counts, const int* __restrict__ offs,
    const int* __restrict__ slot_tok, const float* __restrict__ slot_w,
    float* __restrict__ out) {
  int e = blockIdx.z;
  int ne = counts[e];
  int m0 = blockIdx.y * 128;
  if (m0 >= ne) return;
  int n0 = blockIdx.x * 128;
  __shared__ u16 sAh[128 * 32], sAl[128 * 32], sBh[128 * 32], sBl[128 * 32];
  int tid = threadIdx.x;
  int base = offs[e];
  int ar0 = tid >> 2, ac = (tid & 3) * 8;
  int ar1 = ar0 + 64;
  int i0 = m0 + ar0; if (i0 > ne - 1) i0 = ne - 1;
  int i1 = m0 + ar1; if (i1 > ne - 1) i1 = ne - 1;
  size_t rowA0 = (size_t)(base + i0);
  size_t rowA1 = (size_t)(base + i1);
  const float* W2 = w2 + (size_t)e * HD * FDIM;
  int wid = tid >> 6, lane = tid & 63;
  int wr = (wid >> 1) * 64, wc = (wid & 1) * 64;
  int fr = lane & 15, fk = (lane >> 4) * 8;
  f32x4 acc[4][4] = {};
  for (int k0 = 0; k0 < FDIM; k0 += 32) {
    GLL16(acth + rowA0 * FDIM + k0 + ac, sAh + tid * 8);
    GLL16(acth + rowA1 * FDIM + k0 + ac, sAh + (tid + 256) * 8);
    GLL16(actl + rowA0 * FDIM + k0 + ac, sAl + tid * 8);
    GLL16(actl + rowA1 * FDIM + k0 + ac, sAl + (tid + 256) * 8);
    {
      const float* gb0 = W2 + (size_t)(n0 + ar0) * FDIM + k0 + ac;
      const float* gb1 = W2 + (size_t)(n0 + ar1) * FDIM + k0 + ac;
      float f0[8], f1[8];
      *(float4*)&f0[0] = *(const float4*)gb0;
      *(float4*)&f0[4] = *(const float4*)(gb0 + 4);
      *(float4*)&f1[0] = *(const float4*)gb1;
      *(float4*)&f1[4] = *(const float4*)(gb1 + 4);
      u16x8 h0, l0, h1, l1;
      #pragma unroll
      for (int i = 0; i < 8; i++) {
        u16 hh = f2bf(f0[i]); h0[i] = hh; l0[i] = f2bf(f0[i] - bf2f(hh));
        u16 gg = f2bf(f1[i]); h1[i] = gg; l1[i] = f2bf(f1[i] - bf2f(gg));
      }
      *(u16x8*)(sBh + tid * 8) = h0;
      *(u16x8*)(sBl + tid * 8) = l0;
      *(u16x8*)(sBh + (tid + 256) * 8) = h1;
      *(u16x8*)(sBl + (tid + 256) * 8) = l1;
    }
    __syncthreads();
    bf16x8 ah[4], al[4], bh[4], bl[4];
    #pragma unroll
    for (int i = 0; i < 4; i++) {
      int rowA = wr + i * 16 + fr;
      int rowB = wc + i * 16 + fr;
      ah[i] = *(const bf16x8*)(sAh + rowA * 32 + fk);
      al[i] = *(const bf16x8*)(sAl + rowA * 32 + fk);
      bh[i] = *(const bf16x8*)(sBh + rowB * 32 + fk);
      bl[i] = *(const bf16x8*)(sBl + rowB * 32 + fk);
    }
    #pragma unroll
    for (int i = 0; i < 4; i++)
      #pragma unroll
      for (int j = 0; j < 4; j++) {
        acc[i][j] = mfma16(ah[i], bh[j], acc[i][j]);
        acc[i][j] = mfma16(ah[i], bl[j], acc[i][j]);
        acc[i][j] = mfma16(al[i], bh[j], acc[i][j]);
      }
    __syncthreads();
  }
  int cc = lane & 15, cr = (lane >> 4) * 4;
  #pragma unroll
  for (int i = 0; i < 4; i++) {
    #pragma unroll
    for (int r = 0; r < 4; r++) {
      int gm = m0 + wr + i * 16 + cr + r;
      if (gm >= ne) continue;
      int tok = slot_tok[base + gm];
      float wt = slot_w[base + gm];
      #pragma unroll
      for (int j = 0; j < 4; j++) {
        int gn = n0 + wc + j * 16 + cc;
        atomicAdd(&out[(size_t)tok * HD + gn], wt * acc[i][j][r]);
      }
    }
  }
}

// ---------------- launch -----------------------------------------------------
extern "C" void kernel_launch(void* const* d_in, const int* in_sizes, int n_in,
                              void* d_out, int out_size, void* d_ws, size_t ws_size,
                              hipStream_t stream) {
  const float* hidden = (const float*)d_in[0];
  const float* ln1_w  = (const float*)d_in[1];
  const float* ln2_w  = (const float*)d_in[2];
  const float* q_w    = (const float*)d_in[3];
  const float* k_w    = (const float*)d_in[4];
  const float* v_w    = (const float*)d_in[5];
  const float* o_w    = (const float*)d_in[6];
  const float* gate_w = (const float*)d_in[7];
  const float* w1     = (const float*)d_in[8];
  const float* w3     = (const float*)d_in[9];   // dict order: w1, w3, w2
  const float* w2     = (const float*)d_in[10];
  float* out = (float*)d_out;

  char* ws = (char*)d_ws;
  size_t off = 0;
  auto alloc = [&](size_t bytes) -> char* {
    char* p = ws + off;
    off += (bytes + 255) & ~(size_t)255;
    return p;
  };
  // bufA halves: xh/xl -> atth/attl -> x2h/x2l  (sequential lifetimes)
  u16* bufA0 = (u16*)alloc((size_t)S_LEN * HD * 2);
  u16* bufA1 = (u16*)alloc((size_t)S_LEN * HD * 2);
  float* qb  = (float*)alloc((size_t)S_LEN * HD * 4);   // q  -> x2 fp32
  float* kb  = (float*)alloc((size_t)S_LEN * KVW * 4);
  float* vb  = (float*)alloc((size_t)S_LEN * KVW * 4);
  float* hbuf= (float*)alloc((size_t)S_LEN * HD * 4);   // attn fp32 -> hb
  u16* wqh = (u16*)alloc((size_t)HD * HD * 2);
  u16* wql = (u16*)alloc((size_t)HD * HD * 2);
  u16* wkh = (u16*)alloc((size_t)KVW * HD * 2);
  u16* wkl = (u16*)alloc((size_t)KVW * HD * 2);
  u16* wvh = (u16*)alloc((size_t)KVW * HD * 2);
  u16* wvl = (u16*)alloc((size_t)KVW * HD * 2);
  u16* woh = (u16*)alloc((size_t)HD * HD * 2);
  u16* wol = (u16*)alloc((size_t)HD * HD * 2);
  u16* acth = (u16*)alloc((size_t)2 * S_LEN * FDIM * 2);
  u16* actl = (u16*)alloc((size_t)2 * S_LEN * FDIM * 2);
  int*   tok_e    = (int*)alloc(2 * S_LEN * 4);
  float* tok_w    = (float*)alloc(2 * S_LEN * 4);
  int*   slot_tok = (int*)alloc(2 * S_LEN * 4);
  float* slot_w   = (float*)alloc(2 * S_LEN * 4);
  int*   counts   = (int*)alloc(NE * 4);
  int*   offs     = (int*)alloc(NE * 4);
  int*   ctr2     = (int*)alloc(NE * 4);

  // --- weight splits (small weights only; w1/w3/w2 split on the fly) ---
  cvt_split_kernel<<<512, 256, 0, stream>>>(q_w, wqh, wql, (size_t)HD * HD / 4);
  cvt_split_kernel<<<512, 256, 0, stream>>>(k_w, wkh, wkl, (size_t)KVW * HD / 4);
  cvt_split_kernel<<<512, 256, 0, stream>>>(v_w, wvh, wvl, (size_t)KVW * HD / 4);
  cvt_split_kernel<<<512, 256, 0, stream>>>(o_w, woh, wol, (size_t)HD * HD / 4);

  // --- attention block ---
  rmsnorm_split_kernel<<<S_LEN, 256, 0, stream>>>(hidden, ln1_w, nullptr, bufA0, bufA1);
  gemm_mfma<<<dim3(HD / 128, S_LEN / 128), 256, 0, stream>>>(bufA0, bufA1, wqh, wql,
      nullptr, qb, nullptr, S_LEN, HD, HD);
  gemm_mfma<<<dim3(KVW / 128, S_LEN / 128), 256, 0, stream>>>(bufA0, bufA1, wkh, wkl,
      nullptr, kb, nullptr, S_LEN, KVW, HD);
  gemm_mfma<<<dim3(KVW / 128, S_LEN / 128), 256, 0, stream>>>(bufA0, bufA1, wvh, wvl,
      nullptr, vb, nullptr, S_LEN, KVW, HD);
  rope_kernel<<<S_LEN, 256, 0, stream>>>(qb, kb);
  attn_kernel<<<dim3(S_LEN / QT, NH), 256, 0, stream>>>(qb, kb, vb, hbuf);
  cvt_split_kernel<<<512, 256, 0, stream>>>(hbuf, bufA0, bufA1, (size_t)S_LEN * HD / 4);
  // h = hidden + attn @ o_w^T  (C -> hbuf, C2 -> out seed)
  gemm_mfma<<<dim3(HD / 128, S_LEN / 128), 256, 0, stream>>>(bufA0, bufA1, woh, wol,
      hidden, hbuf, out, S_LEN, HD, HD);

  // --- MoE block ---
  rmsnorm_split_kernel<<<S_LEN, 256, 0, stream>>>(hbuf, ln2_w, qb, bufA0, bufA1);
  zero_counts_kernel<<<1, 64, 0, stream>>>(counts);
  route_kernel<<<S_LEN, 256, 0, stream>>>(qb, gate_w, tok_e, tok_w, counts);
  offsets_kernel<<<1, 64, 0, stream>>>(counts, offs, ctr2);
  scatter_kernel<<<(2 * S_LEN + 255) / 256, 256, 0, stream>>>(tok_e, tok_w, offs, ctr2,
      slot_tok, slot_w);
  moe1_mfma<<<dim3(FDIM / 64, S_LEN / 128, NE), 256, 0, stream>>>(bufA0, bufA1, w1, w3,
      counts, offs, slot_tok, acth, actl);
  moe2_mfma<<<dim3(HD / 128, S_LEN / 128, NE), 256, 0, stream>>>(acth, actl, w2,
      counts, offs, slot_tok, slot_w, out);
}